// Round 12
// baseline (199.447 us; speedup 1.0000x reference)
//
#include <hip/hip_runtime.h>

// ---------------------------------------------------------------------------
// HybridLossDynamic: total = mse + ssim_loss + 0.7*gme over (2,1,128,128,128)
// fp32 volumes. Outputs: [total, mse, ssim_loss, gme].
//
// Pipeline (all on `stream`, both batches merged per launch):
//   k_init        : zero bin accumulators, min=+inf / max=0
//   k_wblur_mse   : W-blur of {p,t,p2,t2,pt} -> A[5xVOL] fp16 + MSE reduce
//                   (r8 proven version: pipelined row loads, hoisted pads)
//   k_blur_y      : y-blur A -> B. r12: ONE FIELD PER BLOCK (grid x5),
//                   LDS 6.7 KB -> 8 blocks/CU (wave-limit occupancy).
//   k_zblur_ssim  : z-blur B + SSIM. r12: per-field-sequential 6.7 KB slab,
//                   8 blocks/CU; m[q] accumulated in registers.
//   k_sobel       : separable Sobel, z-streamed+pipelined. r12: 16-z
//                   segments (2048 blocks, 8/CU) for 2x co-residency.
//   k_edge_diff   : |norm_p - norm_t| reduce (h8)
//   k_final       : fold bins, write 4 outputs
//
// History: r7 fused y+z (scattered 16B HBM reads) regressed; r9-r11 fused
// x+y (63 KB LDS -> 2 blocks/CU, occupancy 17.5%) regressed. Lesson: keep
// slab kernels thin (LDS <= ~8 KB), staging line-contiguous, occupancy at
// the wave limit. This round applies that lesson to the r8 split structure.
//
// ws: A 40 MiB | B 40 MiB (gm reuses B) | accumulators @80 MiB.
// ---------------------------------------------------------------------------

#define VOL 4194304        // 2*128^3 (both batch images)
#define HV  2097152        // one batch image, 128^3

typedef _Float16 h2 __attribute__((ext_vector_type(2)));
typedef _Float16 h8 __attribute__((ext_vector_type(8)));

// 11-tap Gaussian, sigma=1.5, normalized:
constexpr float GW[11] = {
    0.00102838f, 0.00759876f, 0.03600077f, 0.10936070f, 0.21300554f,
    0.26601173f,
    0.21300554f, 0.10936070f, 0.03600077f, 0.00759876f, 0.00102838f};

// Accumulator region layout:
//   dbl[0..511] mse bins | dbl[512..1023] ssim bins | dbl[1024..1535] abs bins
//   ui[0..1023] min v0 | ui[1024..2047] min v1 | ui[2048..3071] max v0 |
//   ui[3072..4095] max v1   (64 bins, 64B stride)

__global__ __launch_bounds__(256) void k_init(double* dbl, unsigned int* ui) {
  const int tid = threadIdx.x + (blockIdx.x << 8);
  if (tid < 1536) dbl[tid] = 0.0;
  if (tid < 4096) ui[tid] = (tid < 2048) ? 0x7F800000u : 0u;
}

// ---- K1: blur along W (contiguous) for 5 fields + MSE partial (both b) -----
__global__ __launch_bounds__(256) void k_wblur_mse(
    const float* __restrict__ p, const float* __restrict__ t,
    _Float16* __restrict__ A, double* __restrict__ mseB) {
  __shared__ float pr[2][138];
  __shared__ float tr[2][138];
  __shared__ float red[256];
  const int tid = threadIdx.x;
  const int rl = tid >> 7;
  const int x  = tid & 127;
  const int rowBase = blockIdx.x << 4;
  if (x < 5)    { pr[rl][x] = 0.f;      tr[rl][x] = 0.f; }
  if (x >= 123) { pr[rl][10 + x] = 0.f; tr[rl][10 + x] = 0.f; }
  float pv = p[((rowBase + rl) << 7) + x];
  float tv = t[((rowBase + rl) << 7) + x];
  float msel = 0.f;
  for (int it = 0; it < 8; ++it) {           // 16 rows per block
    const int row  = rowBase + (it << 1) + rl;
    const int base = row << 7;
    pr[rl][5 + x] = pv; tr[rl][5 + x] = tv;
    __syncthreads();
    float pvN = 0.f, tvN = 0.f;
    if (it < 7) {                            // prefetch next pair (overlaps)
      const int baseN = (row + 2) << 7;
      pvN = p[baseN + x]; tvN = t[baseN + x];
    }
    float ap = 0.f, at = 0.f, app = 0.f, att = 0.f, apt = 0.f;
#pragma unroll
    for (int k = 0; k < 11; ++k) {
      const float w = GW[k];
      const float a = pr[rl][x + k];
      const float b = tr[rl][x + k];
      ap += w * a; at += w * b;
      app += w * a * a; att += w * b * b; apt += w * a * b;
    }
    const int idx = base + x;
    A[idx]           = (_Float16)ap;
    A[VOL + idx]     = (_Float16)at;
    A[2 * VOL + idx] = (_Float16)app;
    A[3 * VOL + idx] = (_Float16)att;
    A[4 * VOL + idx] = (_Float16)apt;
    const float d = pv - tv;
    msel += d * d;
    __syncthreads();
    pv = pvN; tv = tvN;
  }
  red[tid] = msel;
  __syncthreads();
  for (int s = 128; s > 0; s >>= 1) {
    if (tid < s) red[tid] += red[tid + s];
    __syncthreads();
  }
  if (tid == 0) atomicAdd(&mseB[(blockIdx.x & 63) << 3], (double)red[0]);
}

// ---- K2a: y-blur A -> B, ONE FIELD PER BLOCK, 6.7 KB slab ------------------
// grid dim3(128, 40, 2): z-slice, field*8 + y-segment, batch.
__global__ __launch_bounds__(256) void k_blur_y(
    const _Float16* __restrict__ A, _Float16* __restrict__ B) {
  __shared__ h8 s[26][16];      // 6,656 B -> 8 blocks/CU
  const int tid = threadIdx.x;
  const int z  = blockIdx.x;
  const int q  = blockIdx.y >> 3;             // field 0..4
  const int y0 = (blockIdx.y & 7) << 4;
  const int b8 = blockIdx.z << 18;            // batch base in h8 units
  const int slice8 = b8 + (z << 11);
  const h8* __restrict__ Aq = (const h8*)A + (q << 19) + slice8;
  for (int l = tid; l < 416; l += 256) {      // 26 rows x 16 h8
    const int row = l >> 4, xc = l & 15;
    const int y = y0 - 5 + row;
    h8 v{};
    if ((unsigned)y < 128u) v = Aq[(y << 4) + xc];
    s[row][xc] = v;
  }
  __syncthreads();
  const int xc = tid & 15;
  const int yo = tid >> 4;                    // 0..15
  h8 acc{};
#pragma unroll
  for (int k = 0; k < 11; ++k) {
    const _Float16 w = (_Float16)GW[k];
    acc += w * s[yo + k][xc];                 // v_pk_fma_f16 x4
  }
  ((h8*)B)[(q << 19) + slice8 + ((y0 + yo) << 4) + xc] = acc;
}

// ---- K2b: z-blur B, per-field-sequential 6.7 KB slab + SSIM + reduce -------
// grid dim3(128, 8, 2): y-row, z-segment, batch.
__global__ __launch_bounds__(256) void k_zblur_ssim(
    const _Float16* __restrict__ B, double* __restrict__ ssimB) {
  __shared__ h8 s[26][16];      // 6,656 B -> 8 blocks/CU
  __shared__ float red[256];
  const int tid = threadIdx.x;
  const int y  = blockIdx.x;
  const int z0 = blockIdx.y << 4;
  const int b8 = blockIdx.z << 18;            // h8 units
  const h8* __restrict__ Bh = (const h8*)B;
  const int col8 = b8 + (y << 4);
  const int xc = tid & 15;
  const int zo = tid >> 4;                    // 0..15
  h8 m[5];
  for (int q = 0; q < 5; ++q) {
    const h8* __restrict__ Bq = Bh + (q << 19) + col8;
    for (int l = tid; l < 416; l += 256) {    // 26 z-rows x 16 h8
      const int row = l >> 4, xcs = l & 15;
      const int zz = z0 - 5 + row;
      h8 v{};
      if ((unsigned)zz < 128u) v = Bq[(zz << 11) + xcs];
      s[row][xcs] = v;
    }
    __syncthreads();
    h8 acc{};
#pragma unroll
    for (int k = 0; k < 11; ++k) {
      const _Float16 w = (_Float16)GW[k];
      acc += w * s[zo + k][xc];
    }
    m[q] = acc;
    __syncthreads();                          // drain reads before re-stage
  }
  float lsum = 0.f;
#pragma unroll
  for (int j = 0; j < 8; ++j) {
    const float mp  = (float)m[0][j];
    const float mt  = (float)m[1][j];
    const float epp = (float)m[2][j];
    const float ett = (float)m[3][j];
    const float ept = (float)m[4][j];
    const float mp2 = mp * mp, mt2 = mt * mt, mpt = mp * mt;
    const float num = (2.f * mpt + 1e-4f) * (2.f * (ept - mpt) + 9e-4f);
    const float den = (mp2 + mt2 + 1e-4f) * ((epp - mp2) + (ett - mt2) + 9e-4f);
    lsum += num / den;
  }
  red[tid] = lsum;
  __syncthreads();
  for (int st = 128; st > 0; st >>= 1) {
    if (tid < st) red[tid] += red[tid + st];
    __syncthreads();
  }
  if (tid == 0) {
    const int bin = (blockIdx.x + (blockIdx.y << 3) + blockIdx.z) & 63;
    atomicAdd(&ssimB[bin << 3], (double)red[0]);
  }
}

// ---- E1: Sobel via separable s/d/u decomposition, z-streamed, fp16 out -----
// r12: 16-z segments -> 2048 blocks (8/CU). grid dim3(8, 8, 32).
__global__ __launch_bounds__(256) void k_sobel(
    const float* __restrict__ p, const float* __restrict__ t,
    _Float16* __restrict__ gmP, _Float16* __restrict__ gmT,
    unsigned int* __restrict__ ui) {
  __shared__ float sb[972];     // 3 x 18*18 slice buffers
  __shared__ float rmin[256];
  __shared__ float rmax[256];
  const int tid = threadIdx.x;
  const int tx = tid & 15;
  const int ty = tid >> 4;
  const int x0 = blockIdx.x << 4;
  const int y0 = blockIdx.y << 4;
  const int vol = blockIdx.z >> 4;
  const int b   = (blockIdx.z >> 3) & 1;
  const int z0  = (blockIdx.z & 7) << 4;
  const float* __restrict__ img = vol ? t : p;
  _Float16* __restrict__ gm = vol ? gmT : gmP;
  const int vb = b << 21;

  const int l1 = tid;
  const int ly1 = l1 / 18, lx1 = l1 % 18;
  int gy1 = y0 - 1 + ly1; gy1 = gy1 < 0 ? 1 : (gy1 > 127 ? 126 : gy1);
  int gx1 = x0 - 1 + lx1; gx1 = gx1 < 0 ? 1 : (gx1 > 127 ? 126 : gx1);
  const int off1 = (gy1 << 7) + gx1;
  const int l2 = tid + 256;
  const int ly2 = l2 / 18, lx2 = l2 % 18;
  int gy2 = y0 - 1 + ly2; gy2 = gy2 < 0 ? 1 : (gy2 > 127 ? 126 : gy2);
  int gx2 = x0 - 1 + lx2; gx2 = gx2 < 0 ? 1 : (gx2 > 127 ? 126 : gx2);
  const int off2 = (gy2 << 7) + gx2;
  const bool has2 = (tid < 68);
  const int rb = ty * 18 + tx;
  const int gbase = vb + (z0 << 14) + ((y0 + ty) << 7) + (x0 + tx);

  float Y0[7], Y1[7], Y2[7];
  float rv1 = 0.f, rv2 = 0.f;
  float lmin = 3.4e38f, lmax = 0.f;

#define LOADR(ZS) {                                                         \
    const int zc_ = (ZS) > 127 ? 126 : (ZS);                                \
    const int za_ = vb + (zc_ << 14);                                       \
    rv1 = img[za_ + off1];                                                  \
    if (has2) rv2 = img[za_ + off2]; }

#define WRITELDS(BOFF) {                                                    \
    sb[(BOFF) + l1] = rv1;                                                  \
    if (has2) sb[(BOFF) + l2] = rv2; }

#define COMPY(P) {                                                          \
    const int o_ = (P) * 324 + rb;                                          \
    const float r00 = sb[o_],      r01 = sb[o_ + 1],  r02 = sb[o_ + 2];     \
    const float r10 = sb[o_ + 18], r11 = sb[o_ + 19], r12 = sb[o_ + 20];    \
    const float r20 = sb[o_ + 36], r21 = sb[o_ + 37], r22 = sb[o_ + 38];    \
    const float dx0 = r02 - r00, dx1 = r12 - r10, dx2 = r22 - r20;          \
    const float ux0 = r00 + r01 + r02, ux1 = r10 + r11 + r12,               \
                ux2 = r20 + r21 + r22;                                      \
    const float sx0 = ux0 + r01, sx1 = ux1 + r11, sx2 = ux2 + r21;          \
    Y##P[1] = dx0 + dx1 + dx2;           /* uydx */                         \
    Y##P[0] = Y##P[1] + dx1;             /* sydx */                         \
    Y##P[2] = sx2 - sx0;                 /* dysx */                         \
    Y##P[4] = sx0 + sx1 + sx2;           /* uysx */                         \
    Y##P[3] = Y##P[4] + sx1;             /* sysx */                         \
    Y##P[5] = ux2 - ux0;                 /* dyux */                         \
    Y##P[6] = (ux0 + ux2) + 2.f * ux1; } /* syux */

#define EMIT(I, P0, P1, P2) {                                               \
    const float E_ = Y##P0[0] + Y##P1[0] + Y##P2[0];                        \
    const float g1 = E_ + Y##P1[0];                                         \
    const float tA = Y##P0[1] + Y##P1[1] + Y##P2[1];                        \
    const float A_ = tA + Y##P1[1];                                         \
    const float D_ = Y##P0[2] + Y##P1[2] + Y##P2[2];                        \
    const float g2 = D_ + Y##P1[2];                                         \
    const float g3 = Y##P2[3] - Y##P0[3];                                   \
    const float C_ = Y##P2[4] - Y##P0[4];                                   \
    const float B_ = (Y##P0[5] + Y##P2[5]) + 2.f * Y##P1[5];                \
    const float F_ = Y##P2[6] - Y##P0[6];                                   \
    const float g4 = A_ - B_, g5 = A_ + B_;                                 \
    const float g6 = C_ - D_, g7 = C_ + D_;                                 \
    const float g8 = E_ - F_, g9 = E_ + F_;                                 \
    float ss_ = 9e-6f, t_;                                                  \
    t_ = g1 + 1e-6f; ss_ = fmaf(t_, t_, ss_);                               \
    t_ = g2 + 1e-6f; ss_ = fmaf(t_, t_, ss_);                               \
    t_ = g3 + 1e-6f; ss_ = fmaf(t_, t_, ss_);                               \
    t_ = g4 + 1e-6f; ss_ = fmaf(t_, t_, ss_);                               \
    t_ = g5 + 1e-6f; ss_ = fmaf(t_, t_, ss_);                               \
    t_ = g6 + 1e-6f; ss_ = fmaf(t_, t_, ss_);                               \
    t_ = g7 + 1e-6f; ss_ = fmaf(t_, t_, ss_);                               \
    t_ = g8 + 1e-6f; ss_ = fmaf(t_, t_, ss_);                               \
    t_ = g9 + 1e-6f; ss_ = fmaf(t_, t_, ss_);                               \
    const _Float16 gh = (_Float16)sqrtf(ss_);                               \
    gm[gbase + ((I) << 14)] = gh;                                           \
    const float gq = (float)gh;                                             \
    lmin = fminf(lmin, gq); lmax = fmaxf(lmax, gq); }

#define BODY(I, P0, P1, P2) {                                               \
    WRITELDS((P2) * 324);                                                   \
    LOADR(z0 + (I) + 2);                                                    \
    __syncthreads();                                                        \
    COMPY(P2);                                                              \
    EMIT(I, P0, P1, P2); }

  {
    const int zp = (z0 == 0) ? 1 : (z0 - 1);
    LOADR(zp);  WRITELDS(0);
    LOADR(z0);  WRITELDS(324);
    __syncthreads();
    COMPY(0);
    COMPY(1);
    LOADR(z0 + 1);
  }
  for (int ii = 0; ii < 15; ii += 3) {
    BODY(ii,     0, 1, 2);
    BODY(ii + 1, 1, 2, 0);
    BODY(ii + 2, 2, 0, 1);
  }
  BODY(15, 0, 1, 2);

#undef BODY
#undef EMIT
#undef COMPY
#undef WRITELDS
#undef LOADR

  rmin[tid] = lmin; rmax[tid] = lmax;
  __syncthreads();
  for (int st = 128; st > 0; st >>= 1) {
    if (tid < st) {
      rmin[tid] = fminf(rmin[tid], rmin[tid + st]);
      rmax[tid] = fmaxf(rmax[tid], rmax[tid + st]);
    }
    __syncthreads();
  }
  if (tid == 0) {
    const int bin = (blockIdx.x + (blockIdx.y << 3) + (blockIdx.z << 6)) & 63;
    atomicMin(&ui[vol * 1024 + (bin << 4)], __float_as_uint(rmin[0]));
    atomicMax(&ui[2048 + vol * 1024 + (bin << 4)], __float_as_uint(rmax[0]));
  }
}

// ---- E2: mean |norm_p - norm_t| (h8 loads) ---------------------------------
__global__ __launch_bounds__(256) void k_edge_diff(
    const _Float16* __restrict__ gmP, const _Float16* __restrict__ gmT,
    const unsigned int* __restrict__ ui, double* __restrict__ absB) {
  float mnp = 3.4e38f, mnt = 3.4e38f, mxp = 0.f, mxt = 0.f;
  for (int j = 0; j < 64; ++j) {
    mnp = fminf(mnp, __uint_as_float(ui[j << 4]));
    mnt = fminf(mnt, __uint_as_float(ui[1024 + (j << 4)]));
    mxp = fmaxf(mxp, __uint_as_float(ui[2048 + (j << 4)]));
    mxt = fmaxf(mxt, __uint_as_float(ui[3072 + (j << 4)]));
  }
  const float scp = 1.f / (mxp - mnp + 1e-6f);
  const float sct = 1.f / (mxt - mnt + 1e-6f);
  const h8* __restrict__ gp = (const h8*)gmP;
  const h8* __restrict__ gt = (const h8*)gmT;
  float lsum = 0.f;
  const int base = blockIdx.x << 9;                // 512 h8 per block
#pragma unroll
  for (int i = 0; i < 2; ++i) {
    const int idx = base + (i << 8) + threadIdx.x;
    const h8 a = gp[idx];
    const h8 b = gt[idx];
#pragma unroll
    for (int j = 0; j < 8; ++j)
      lsum += fabsf(((float)a[j] - mnp) * scp - ((float)b[j] - mnt) * sct);
  }
  __shared__ float red[256];
  red[threadIdx.x] = lsum;
  __syncthreads();
  for (int s = 128; s > 0; s >>= 1) {
    if (threadIdx.x < s) red[threadIdx.x] += red[threadIdx.x + s];
    __syncthreads();
  }
  if (threadIdx.x == 0)
    atomicAdd(&absB[(blockIdx.x & 63) << 3], (double)red[0]);
}

// ---- final: fold bins, emit the 4 scalars ----------------------------------
__global__ void k_final(const double* __restrict__ dbl, float* __restrict__ out) {
  if (threadIdx.x == 0 && blockIdx.x == 0) {
    double ms = 0.0, ss = 0.0, ab = 0.0;
    for (int j = 0; j < 64; ++j) {
      ms += dbl[j << 3];
      ss += dbl[512 + (j << 3)];
      ab += dbl[1024 + (j << 3)];
    }
    const double N = 4194304.0;
    const double mse   = ms / N;
    const double ssiml = 1.0 - ss / N;
    const double gme   = 1e-6 + ab / N;
    const double total = mse + ssiml + 0.7 * gme;
    out[0] = (float)total;
    out[1] = (float)mse;
    out[2] = (float)ssiml;
    out[3] = (float)gme;
  }
}

extern "C" void kernel_launch(void* const* d_in, const int* in_sizes, int n_in,
                              void* d_out, int out_size, void* d_ws, size_t ws_size,
                              hipStream_t stream) {
  const float* p = (const float*)d_in[0];
  const float* t = (const float*)d_in[1];
  _Float16* A = (_Float16*)d_ws;                    // 5*VOL halfs = 40 MiB
  _Float16* B = A + (size_t)5 * VOL;                // 40 MiB
  char* accb = (char*)d_ws + (size_t)20 * VOL;      // 83,886,080
  double* dbl = (double*)accb;
  unsigned int* ui = (unsigned int*)(accb + 12288);
  float* out = (float*)d_out;
  _Float16* gmP = B;                // reuse B space after zblur consumed it
  _Float16* gmT = gmP + VOL;

  k_init<<<16, 256, 0, stream>>>(dbl, ui);
  k_wblur_mse<<<2048, 256, 0, stream>>>(p, t, A, dbl);
  k_blur_y<<<dim3(128, 40, 2), 256, 0, stream>>>(A, B);
  k_zblur_ssim<<<dim3(128, 8, 2), 256, 0, stream>>>(B, dbl + 512);
  k_sobel<<<dim3(8, 8, 32), 256, 0, stream>>>(p, t, gmP, gmT, ui);
  k_edge_diff<<<1024, 256, 0, stream>>>(gmP, gmT, ui, dbl + 1024);
  k_final<<<1, 64, 0, stream>>>(dbl, out);
}

// Round 13
// 164.117 us; speedup vs baseline: 1.2153x; 1.2153x over previous
//
#include <hip/hip_runtime.h>

// ---------------------------------------------------------------------------
// HybridLossDynamic: total = mse + ssim_loss + 0.7*gme over (2,1,128,128,128)
// fp32 volumes. Outputs: [total, mse, ssim_loss, gme].
//
// This is the r8 configuration (best measured: 167.2 us), restored exactly.
//
// Pipeline (all on `stream`, both batches merged per launch):
//   k_init        : zero bin accumulators, min=+inf / max=0
//   k_wblur_mse   : W-blur of {p,t,p2,t2,pt} -> A[5xVOL] fp16 + MSE reduce
//                   (pipelined row loads, hoisted pads)
//   k_blur_y      : y-blur A -> B, 5-field 33KB h8 slab, b128 + pk_fma_f16
//   k_zblur_ssim  : z-blur B, 5-field 33KB h8 slab, pk_fma + fp32 SSIM + red
//   k_sobel       : separable Sobel (s/d/u decomposition), z-streamed,
//                   pipelined staging (load->reg, write->LDS, prefetch next)
//   k_edge_diff   : |norm_p - norm_t| reduce (h8)
//   k_final       : fold bins, write 4 outputs
//
// Measured lessons pinned (do not revisit):
//   r7:  fusing y+z blur -> scattered 16B staging reads, 200MB HBM, REGRESSED
//   r9:  last-block final fold + stride-2 LDS windows, REGRESSED
//   r10/r11: x+y fusion = 63KB LDS -> 2 blocks/CU, occupancy 17.5%, REGRESSED
//   r12: per-field thin slabs (8 blocks/CU) -> 5x barrier-latency exposure,
//        zblur 18->70us. MLP per barrier interval >> occupancy. REGRESSED
//
// ws: A 40 MiB | B 40 MiB (gm volumes reuse B after zblur) | acc @80 MiB.
// ---------------------------------------------------------------------------

#define VOL 4194304        // 2*128^3 (both batch images)
#define HV  2097152        // one batch image, 128^3

typedef _Float16 h2 __attribute__((ext_vector_type(2)));
typedef _Float16 h8 __attribute__((ext_vector_type(8)));

// 11-tap Gaussian, sigma=1.5, normalized:
constexpr float GW[11] = {
    0.00102838f, 0.00759876f, 0.03600077f, 0.10936070f, 0.21300554f,
    0.26601173f,
    0.21300554f, 0.10936070f, 0.03600077f, 0.00759876f, 0.00102838f};

// Accumulator region layout:
//   dbl[0..511] mse bins | dbl[512..1023] ssim bins | dbl[1024..1535] abs bins
//   ui[0..1023] min v0 | ui[1024..2047] min v1 | ui[2048..3071] max v0 |
//   ui[3072..4095] max v1   (64 bins, 64B stride)

__global__ __launch_bounds__(256) void k_init(double* dbl, unsigned int* ui) {
  const int tid = threadIdx.x + (blockIdx.x << 8);
  if (tid < 1536) dbl[tid] = 0.0;
  if (tid < 4096) ui[tid] = (tid < 2048) ? 0x7F800000u : 0u;
}

// ---- K1: blur along W (contiguous) for 5 fields + MSE partial (both b) -----
__global__ __launch_bounds__(256) void k_wblur_mse(
    const float* __restrict__ p, const float* __restrict__ t,
    _Float16* __restrict__ A, double* __restrict__ mseB) {
  __shared__ float pr[2][138];
  __shared__ float tr[2][138];
  __shared__ float red[256];
  const int tid = threadIdx.x;
  const int rl = tid >> 7;
  const int x  = tid & 127;
  const int rowBase = blockIdx.x << 4;
  if (x < 5)    { pr[rl][x] = 0.f;      tr[rl][x] = 0.f; }
  if (x >= 123) { pr[rl][10 + x] = 0.f; tr[rl][10 + x] = 0.f; }
  float pv = p[((rowBase + rl) << 7) + x];
  float tv = t[((rowBase + rl) << 7) + x];
  float msel = 0.f;
  for (int it = 0; it < 8; ++it) {           // 16 rows per block
    const int row  = rowBase + (it << 1) + rl;
    const int base = row << 7;
    pr[rl][5 + x] = pv; tr[rl][5 + x] = tv;
    __syncthreads();
    float pvN = 0.f, tvN = 0.f;
    if (it < 7) {                            // prefetch next pair (overlaps)
      const int baseN = (row + 2) << 7;
      pvN = p[baseN + x]; tvN = t[baseN + x];
    }
    float ap = 0.f, at = 0.f, app = 0.f, att = 0.f, apt = 0.f;
#pragma unroll
    for (int k = 0; k < 11; ++k) {
      const float w = GW[k];
      const float a = pr[rl][x + k];
      const float b = tr[rl][x + k];
      ap += w * a; at += w * b;
      app += w * a * a; att += w * b * b; apt += w * a * b;
    }
    const int idx = base + x;
    A[idx]           = (_Float16)ap;
    A[VOL + idx]     = (_Float16)at;
    A[2 * VOL + idx] = (_Float16)app;
    A[3 * VOL + idx] = (_Float16)att;
    A[4 * VOL + idx] = (_Float16)apt;
    const float d = pv - tv;
    msel += d * d;
    __syncthreads();
    pv = pvN; tv = tvN;
  }
  red[tid] = msel;
  __syncthreads();
  for (int s = 128; s > 0; s >>= 1) {
    if (tid < s) red[tid] += red[tid + s];
    __syncthreads();
  }
  if (tid == 0) atomicAdd(&mseB[(blockIdx.x & 63) << 3], (double)red[0]);
}

// ---- K2a: y-blur A -> B, h8 slab, b128 LDS + packed-fp16 taps --------------
// grid dim3(128, 8, 2): z-slice, y-segment, batch. Thread owns (yo, 8-x group).
__global__ __launch_bounds__(256) void k_blur_y(
    const _Float16* __restrict__ A, _Float16* __restrict__ B) {
  __shared__ h8 s[5][26][16];   // 33,280 B
  const int tid = threadIdx.x;
  const int z  = blockIdx.x;
  const int y0 = blockIdx.y << 4;
  const int b8 = blockIdx.z << 18;            // batch base in h8 units (HV/8)
  const h8* __restrict__ Ah = (const h8*)A;
  h8* __restrict__ Bh = (h8*)B;
  const int slice8 = b8 + (z << 11);          // h8 index of (b,z,0,0)
  for (int q = 0; q < 5; ++q) {
    const h8* __restrict__ Aq = Ah + (q << 19) + slice8;
    for (int l = tid; l < 416; l += 256) {    // 26 rows x 16 h8
      const int row = l >> 4, xc = l & 15;
      const int y = y0 - 5 + row;
      h8 v{};
      if ((unsigned)y < 128u) v = Aq[(y << 4) + xc];
      s[q][row][xc] = v;
    }
  }
  __syncthreads();
  const int xc = tid & 15;
  const int yo = tid >> 4;                    // 0..15
  const int wbase = slice8 + ((y0 + yo) << 4) + xc;
#pragma unroll
  for (int q = 0; q < 5; ++q) {
    h8 acc{};
#pragma unroll
    for (int k = 0; k < 11; ++k) {
      const _Float16 w = (_Float16)GW[k];
      acc += w * s[q][yo + k][xc];            // v_pk_fma_f16 x4
    }
    Bh[(q << 19) + wbase] = acc;
  }
}

// ---- K2b: z-blur B, h8 slab, packed-fp16 taps + fp32 SSIM map + reduce -----
// grid dim3(128, 8, 2): y-row, z-segment, batch. Thread owns (zo, 8-x group).
__global__ __launch_bounds__(256) void k_zblur_ssim(
    const _Float16* __restrict__ B, double* __restrict__ ssimB) {
  __shared__ h8 s[5][26][16];   // 33,280 B
  __shared__ float red[256];
  const int tid = threadIdx.x;
  const int y  = blockIdx.x;
  const int z0 = blockIdx.y << 4;
  const int b8 = blockIdx.z << 18;            // h8 units
  const h8* __restrict__ Bh = (const h8*)B;
  const int col8 = b8 + (y << 4);
  for (int q = 0; q < 5; ++q) {
    const h8* __restrict__ Bq = Bh + (q << 19) + col8;
    for (int l = tid; l < 416; l += 256) {    // 26 z-rows x 16 h8
      const int row = l >> 4, xc = l & 15;
      const int zz = z0 - 5 + row;
      h8 v{};
      if ((unsigned)zz < 128u) v = Bq[(zz << 11) + xc];
      s[q][row][xc] = v;
    }
  }
  __syncthreads();
  const int xc = tid & 15;
  const int zo = tid >> 4;                    // 0..15
  h8 m[5];
#pragma unroll
  for (int q = 0; q < 5; ++q) {
    h8 acc{};
#pragma unroll
    for (int k = 0; k < 11; ++k) {
      const _Float16 w = (_Float16)GW[k];
      acc += w * s[q][zo + k][xc];
    }
    m[q] = acc;
  }
  float lsum = 0.f;
#pragma unroll
  for (int j = 0; j < 8; ++j) {
    const float mp  = (float)m[0][j];
    const float mt  = (float)m[1][j];
    const float epp = (float)m[2][j];
    const float ett = (float)m[3][j];
    const float ept = (float)m[4][j];
    const float mp2 = mp * mp, mt2 = mt * mt, mpt = mp * mt;
    const float num = (2.f * mpt + 1e-4f) * (2.f * (ept - mpt) + 9e-4f);
    const float den = (mp2 + mt2 + 1e-4f) * ((epp - mp2) + (ett - mt2) + 9e-4f);
    lsum += num / den;
  }
  red[tid] = lsum;
  __syncthreads();
  for (int st = 128; st > 0; st >>= 1) {
    if (tid < st) red[tid] += red[tid + st];
    __syncthreads();
  }
  if (tid == 0) {
    const int bin = (blockIdx.x + (blockIdx.y << 3) + blockIdx.z) & 63;
    atomicAdd(&ssimB[bin << 3], (double)red[0]);
  }
}

// ---- E1: Sobel via separable s/d/u decomposition, z-streamed, fp16 out -----
// Pipelined: slice I+1's registers are written to LDS, then slice I+2's
// global loads are issued BEFORE the barrier, overlapping COMPY/EMIT.
__global__ __launch_bounds__(256) void k_sobel(
    const float* __restrict__ p, const float* __restrict__ t,
    _Float16* __restrict__ gmP, _Float16* __restrict__ gmT,
    unsigned int* __restrict__ ui) {
  __shared__ float sb[972];     // 3 x 18*18 slice buffers
  __shared__ float rmin[256];
  __shared__ float rmax[256];
  const int tid = threadIdx.x;
  const int tx = tid & 15;
  const int ty = tid >> 4;
  const int x0 = blockIdx.x << 4;
  const int y0 = blockIdx.y << 4;
  const int vol = blockIdx.z >> 3;
  const int b   = (blockIdx.z >> 2) & 1;
  const int z0  = (blockIdx.z & 3) << 5;
  const float* __restrict__ img = vol ? t : p;
  _Float16* __restrict__ gm = vol ? gmT : gmP;
  const int vb = b << 21;

  const int l1 = tid;
  const int ly1 = l1 / 18, lx1 = l1 % 18;
  int gy1 = y0 - 1 + ly1; gy1 = gy1 < 0 ? 1 : (gy1 > 127 ? 126 : gy1);
  int gx1 = x0 - 1 + lx1; gx1 = gx1 < 0 ? 1 : (gx1 > 127 ? 126 : gx1);
  const int off1 = (gy1 << 7) + gx1;
  const int l2 = tid + 256;
  const int ly2 = l2 / 18, lx2 = l2 % 18;
  int gy2 = y0 - 1 + ly2; gy2 = gy2 < 0 ? 1 : (gy2 > 127 ? 126 : gy2);
  int gx2 = x0 - 1 + lx2; gx2 = gx2 < 0 ? 1 : (gx2 > 127 ? 126 : gx2);
  const int off2 = (gy2 << 7) + gx2;
  const bool has2 = (tid < 68);
  const int rb = ty * 18 + tx;
  const int gbase = vb + (z0 << 14) + ((y0 + ty) << 7) + (x0 + tx);

  float Y0[7], Y1[7], Y2[7];
  float rv1 = 0.f, rv2 = 0.f;
  float lmin = 3.4e38f, lmax = 0.f;

#define LOADR(ZS) {                                                         \
    const int zc_ = (ZS) > 127 ? 126 : (ZS);                                \
    const int za_ = vb + (zc_ << 14);                                       \
    rv1 = img[za_ + off1];                                                  \
    if (has2) rv2 = img[za_ + off2]; }

#define WRITELDS(BOFF) {                                                    \
    sb[(BOFF) + l1] = rv1;                                                  \
    if (has2) sb[(BOFF) + l2] = rv2; }

#define COMPY(P) {                                                          \
    const int o_ = (P) * 324 + rb;                                          \
    const float r00 = sb[o_],      r01 = sb[o_ + 1],  r02 = sb[o_ + 2];     \
    const float r10 = sb[o_ + 18], r11 = sb[o_ + 19], r12 = sb[o_ + 20];    \
    const float r20 = sb[o_ + 36], r21 = sb[o_ + 37], r22 = sb[o_ + 38];    \
    const float dx0 = r02 - r00, dx1 = r12 - r10, dx2 = r22 - r20;          \
    const float ux0 = r00 + r01 + r02, ux1 = r10 + r11 + r12,               \
                ux2 = r20 + r21 + r22;                                      \
    const float sx0 = ux0 + r01, sx1 = ux1 + r11, sx2 = ux2 + r21;          \
    Y##P[1] = dx0 + dx1 + dx2;           /* uydx */                         \
    Y##P[0] = Y##P[1] + dx1;             /* sydx */                         \
    Y##P[2] = sx2 - sx0;                 /* dysx */                         \
    Y##P[4] = sx0 + sx1 + sx2;           /* uysx */                         \
    Y##P[3] = Y##P[4] + sx1;             /* sysx */                         \
    Y##P[5] = ux2 - ux0;                 /* dyux */                         \
    Y##P[6] = (ux0 + ux2) + 2.f * ux1; } /* syux */

#define EMIT(I, P0, P1, P2) {                                               \
    const float E_ = Y##P0[0] + Y##P1[0] + Y##P2[0];                        \
    const float g1 = E_ + Y##P1[0];                                         \
    const float tA = Y##P0[1] + Y##P1[1] + Y##P2[1];                        \
    const float A_ = tA + Y##P1[1];                                         \
    const float D_ = Y##P0[2] + Y##P1[2] + Y##P2[2];                        \
    const float g2 = D_ + Y##P1[2];                                         \
    const float g3 = Y##P2[3] - Y##P0[3];                                   \
    const float C_ = Y##P2[4] - Y##P0[4];                                   \
    const float B_ = (Y##P0[5] + Y##P2[5]) + 2.f * Y##P1[5];                \
    const float F_ = Y##P2[6] - Y##P0[6];                                   \
    const float g4 = A_ - B_, g5 = A_ + B_;                                 \
    const float g6 = C_ - D_, g7 = C_ + D_;                                 \
    const float g8 = E_ - F_, g9 = E_ + F_;                                 \
    float ss_ = 9e-6f, t_;                                                  \
    t_ = g1 + 1e-6f; ss_ = fmaf(t_, t_, ss_);                               \
    t_ = g2 + 1e-6f; ss_ = fmaf(t_, t_, ss_);                               \
    t_ = g3 + 1e-6f; ss_ = fmaf(t_, t_, ss_);                               \
    t_ = g4 + 1e-6f; ss_ = fmaf(t_, t_, ss_);                               \
    t_ = g5 + 1e-6f; ss_ = fmaf(t_, t_, ss_);                               \
    t_ = g6 + 1e-6f; ss_ = fmaf(t_, t_, ss_);                               \
    t_ = g7 + 1e-6f; ss_ = fmaf(t_, t_, ss_);                               \
    t_ = g8 + 1e-6f; ss_ = fmaf(t_, t_, ss_);                               \
    t_ = g9 + 1e-6f; ss_ = fmaf(t_, t_, ss_);                               \
    const _Float16 gh = (_Float16)sqrtf(ss_);                               \
    gm[gbase + ((I) << 14)] = gh;                                           \
    const float gq = (float)gh;                                             \
    lmin = fminf(lmin, gq); lmax = fmaxf(lmax, gq); }

// buffer P2 was last read (COMPY) 3 iterations ago — >=2 barriers in between,
// so writing it before this iteration's barrier is safe.
#define BODY(I, P0, P1, P2) {                                               \
    WRITELDS((P2) * 324);                                                   \
    LOADR(z0 + (I) + 2);                                                    \
    __syncthreads();                                                        \
    COMPY(P2);                                                              \
    EMIT(I, P0, P1, P2); }

  {
    const int zp = (z0 == 0) ? 1 : (z0 - 1);
    LOADR(zp);  WRITELDS(0);
    LOADR(z0);  WRITELDS(324);
    __syncthreads();
    COMPY(0);
    COMPY(1);
    LOADR(z0 + 1);                           // prime the pipeline
  }
  for (int ii = 0; ii < 30; ii += 3) {
    BODY(ii,     0, 1, 2);
    BODY(ii + 1, 1, 2, 0);
    BODY(ii + 2, 2, 0, 1);
  }
  BODY(30, 0, 1, 2);
  BODY(31, 1, 2, 0);

#undef BODY
#undef EMIT
#undef COMPY
#undef WRITELDS
#undef LOADR

  rmin[tid] = lmin; rmax[tid] = lmax;
  __syncthreads();
  for (int st = 128; st > 0; st >>= 1) {
    if (tid < st) {
      rmin[tid] = fminf(rmin[tid], rmin[tid + st]);
      rmax[tid] = fmaxf(rmax[tid], rmax[tid + st]);
    }
    __syncthreads();
  }
  if (tid == 0) {
    const int bin = (blockIdx.x + (blockIdx.y << 3) + (blockIdx.z << 6)) & 63;
    atomicMin(&ui[vol * 1024 + (bin << 4)], __float_as_uint(rmin[0]));
    atomicMax(&ui[2048 + vol * 1024 + (bin << 4)], __float_as_uint(rmax[0]));
  }
}

// ---- E2: mean |norm_p - norm_t| (h8 loads) ---------------------------------
__global__ __launch_bounds__(256) void k_edge_diff(
    const _Float16* __restrict__ gmP, const _Float16* __restrict__ gmT,
    const unsigned int* __restrict__ ui, double* __restrict__ absB) {
  float mnp = 3.4e38f, mnt = 3.4e38f, mxp = 0.f, mxt = 0.f;
  for (int j = 0; j < 64; ++j) {
    mnp = fminf(mnp, __uint_as_float(ui[j << 4]));
    mnt = fminf(mnt, __uint_as_float(ui[1024 + (j << 4)]));
    mxp = fmaxf(mxp, __uint_as_float(ui[2048 + (j << 4)]));
    mxt = fmaxf(mxt, __uint_as_float(ui[3072 + (j << 4)]));
  }
  const float scp = 1.f / (mxp - mnp + 1e-6f);
  const float sct = 1.f / (mxt - mnt + 1e-6f);
  const h8* __restrict__ gp = (const h8*)gmP;
  const h8* __restrict__ gt = (const h8*)gmT;
  float lsum = 0.f;
  const int base = blockIdx.x << 9;                // 512 h8 per block
#pragma unroll
  for (int i = 0; i < 2; ++i) {
    const int idx = base + (i << 8) + threadIdx.x;
    const h8 a = gp[idx];
    const h8 b = gt[idx];
#pragma unroll
    for (int j = 0; j < 8; ++j)
      lsum += fabsf(((float)a[j] - mnp) * scp - ((float)b[j] - mnt) * sct);
  }
  __shared__ float red[256];
  red[threadIdx.x] = lsum;
  __syncthreads();
  for (int s = 128; s > 0; s >>= 1) {
    if (threadIdx.x < s) red[threadIdx.x] += red[threadIdx.x + s];
    __syncthreads();
  }
  if (threadIdx.x == 0)
    atomicAdd(&absB[(blockIdx.x & 63) << 3], (double)red[0]);
}

// ---- final: fold bins, emit the 4 scalars ----------------------------------
__global__ void k_final(const double* __restrict__ dbl, float* __restrict__ out) {
  if (threadIdx.x == 0 && blockIdx.x == 0) {
    double ms = 0.0, ss = 0.0, ab = 0.0;
    for (int j = 0; j < 64; ++j) {
      ms += dbl[j << 3];
      ss += dbl[512 + (j << 3)];
      ab += dbl[1024 + (j << 3)];
    }
    const double N = 4194304.0;
    const double mse   = ms / N;
    const double ssiml = 1.0 - ss / N;
    const double gme   = 1e-6 + ab / N;
    const double total = mse + ssiml + 0.7 * gme;
    out[0] = (float)total;
    out[1] = (float)mse;
    out[2] = (float)ssiml;
    out[3] = (float)gme;
  }
}

extern "C" void kernel_launch(void* const* d_in, const int* in_sizes, int n_in,
                              void* d_out, int out_size, void* d_ws, size_t ws_size,
                              hipStream_t stream) {
  const float* p = (const float*)d_in[0];
  const float* t = (const float*)d_in[1];
  _Float16* A = (_Float16*)d_ws;                    // 5*VOL halfs = 40 MiB
  _Float16* B = A + (size_t)5 * VOL;                // 40 MiB
  char* accb = (char*)d_ws + (size_t)20 * VOL;      // 83,886,080
  double* dbl = (double*)accb;
  unsigned int* ui = (unsigned int*)(accb + 12288);
  float* out = (float*)d_out;
  _Float16* gmP = B;                // reuse B space after zblur consumed it
  _Float16* gmT = gmP + VOL;

  k_init<<<16, 256, 0, stream>>>(dbl, ui);
  k_wblur_mse<<<2048, 256, 0, stream>>>(p, t, A, dbl);
  k_blur_y<<<dim3(128, 8, 2), 256, 0, stream>>>(A, B);
  k_zblur_ssim<<<dim3(128, 8, 2), 256, 0, stream>>>(B, dbl + 512);
  k_sobel<<<dim3(8, 8, 16), 256, 0, stream>>>(p, t, gmP, gmT, ui);
  k_edge_diff<<<1024, 256, 0, stream>>>(gmP, gmT, ui, dbl + 1024);
  k_final<<<1, 64, 0, stream>>>(dbl, out);
}

// Round 14
// 162.608 us; speedup vs baseline: 1.2266x; 1.0093x over previous
//
#include <hip/hip_runtime.h>

// ---------------------------------------------------------------------------
// HybridLossDynamic: total = mse + ssim_loss + 0.7*gme over (2,1,128,128,128)
// fp32 volumes. Outputs: [total, mse, ssim_loss, gme].
//
// r14: r8/r13 kernel bodies (proven, 164 us) with INDEPENDENT-CHAIN FUSION:
//   chain 1: wblur -> blur_y -> zblur     chain 2: sobel -> edge_diff
//   L1 = wblur  || sobel      (role-interleaved via bid%3; both read p,t)
//   L2 = blur_y || edge_diff  (both ready after L1; gm moved off B)
//   L3 = zblur, plus init/final. 7 launches -> 5; latency-bound roles
//   co-resident on every CU (time -> max, not sum).
//
// Measured lessons pinned (do not revisit):
//   r7:  y+z fusion -> scattered 16B staging, 200MB HBM. REGRESSED
//   r9:  last-block fold + stride-2 windows. REGRESSED
//   r10/r11: x+y fusion -> 63KB LDS, 2 blocks/CU. REGRESSED
//   r12: thin per-field slabs -> 5x barrier-latency exposure. REGRESSED
//
// ws: A [0,40) MiB | B [40,80) | acc @80 MiB | gm @84 MiB (16 MiB).
// ---------------------------------------------------------------------------

#define VOL 4194304        // 2*128^3 (both batch images)
#define HV  2097152        // one batch image, 128^3

typedef _Float16 h2 __attribute__((ext_vector_type(2)));
typedef _Float16 h8 __attribute__((ext_vector_type(8)));

// 11-tap Gaussian, sigma=1.5, normalized:
constexpr float GW[11] = {
    0.00102838f, 0.00759876f, 0.03600077f, 0.10936070f, 0.21300554f,
    0.26601173f,
    0.21300554f, 0.10936070f, 0.03600077f, 0.00759876f, 0.00102838f};

// Accumulator region layout:
//   dbl[0..511] mse bins | dbl[512..1023] ssim bins | dbl[1024..1535] abs bins
//   ui[0..1023] min v0 | ui[1024..2047] min v1 | ui[2048..3071] max v0 |
//   ui[3072..4095] max v1   (64 bins, 64B stride)

__global__ __launch_bounds__(256) void k_init(double* dbl, unsigned int* ui) {
  const int tid = threadIdx.x + (blockIdx.x << 8);
  if (tid < 1536) dbl[tid] = 0.0;
  if (tid < 4096) ui[tid] = (tid < 2048) ? 0x7F800000u : 0u;
}

// ---- role: W-blur (contiguous axis) for 5 fields + MSE partial -------------
__device__ __forceinline__ void wblur_body(
    const float* __restrict__ p, const float* __restrict__ t,
    _Float16* __restrict__ A, double* __restrict__ mseB, const int bidx) {
  __shared__ float pr[2][138];
  __shared__ float tr[2][138];
  __shared__ float redw[256];
  const int tid = threadIdx.x;
  const int rl = tid >> 7;
  const int x  = tid & 127;
  const int rowBase = bidx << 4;
  if (x < 5)    { pr[rl][x] = 0.f;      tr[rl][x] = 0.f; }
  if (x >= 123) { pr[rl][10 + x] = 0.f; tr[rl][10 + x] = 0.f; }
  float pv = p[((rowBase + rl) << 7) + x];
  float tv = t[((rowBase + rl) << 7) + x];
  float msel = 0.f;
  for (int it = 0; it < 8; ++it) {           // 16 rows per block
    const int row  = rowBase + (it << 1) + rl;
    const int base = row << 7;
    pr[rl][5 + x] = pv; tr[rl][5 + x] = tv;
    __syncthreads();
    float pvN = 0.f, tvN = 0.f;
    if (it < 7) {                            // prefetch next pair (overlaps)
      const int baseN = (row + 2) << 7;
      pvN = p[baseN + x]; tvN = t[baseN + x];
    }
    float ap = 0.f, at = 0.f, app = 0.f, att = 0.f, apt = 0.f;
#pragma unroll
    for (int k = 0; k < 11; ++k) {
      const float w = GW[k];
      const float a = pr[rl][x + k];
      const float b = tr[rl][x + k];
      ap += w * a; at += w * b;
      app += w * a * a; att += w * b * b; apt += w * a * b;
    }
    const int idx = base + x;
    A[idx]           = (_Float16)ap;
    A[VOL + idx]     = (_Float16)at;
    A[2 * VOL + idx] = (_Float16)app;
    A[3 * VOL + idx] = (_Float16)att;
    A[4 * VOL + idx] = (_Float16)apt;
    const float d = pv - tv;
    msel += d * d;
    __syncthreads();
    pv = pvN; tv = tvN;
  }
  redw[tid] = msel;
  __syncthreads();
  for (int s = 128; s > 0; s >>= 1) {
    if (tid < s) redw[tid] += redw[tid + s];
    __syncthreads();
  }
  if (tid == 0) atomicAdd(&mseB[(bidx & 63) << 3], (double)redw[0]);
}

// ---- role: Sobel via separable s/d/u decomposition, z-streamed -------------
__device__ __forceinline__ void sobel_body(
    const float* __restrict__ p, const float* __restrict__ t,
    _Float16* __restrict__ gmP, _Float16* __restrict__ gmT,
    unsigned int* __restrict__ ui, const int bx, const int by, const int bz) {
  __shared__ float sb[972];     // 3 x 18*18 slice buffers
  __shared__ float rmin[256];
  __shared__ float rmax[256];
  const int tid = threadIdx.x;
  const int tx = tid & 15;
  const int ty = tid >> 4;
  const int x0 = bx << 4;
  const int y0 = by << 4;
  const int vol = bz >> 3;
  const int b   = (bz >> 2) & 1;
  const int z0  = (bz & 3) << 5;
  const float* __restrict__ img = vol ? t : p;
  _Float16* __restrict__ gm = vol ? gmT : gmP;
  const int vb = b << 21;

  const int l1 = tid;
  const int ly1 = l1 / 18, lx1 = l1 % 18;
  int gy1 = y0 - 1 + ly1; gy1 = gy1 < 0 ? 1 : (gy1 > 127 ? 126 : gy1);
  int gx1 = x0 - 1 + lx1; gx1 = gx1 < 0 ? 1 : (gx1 > 127 ? 126 : gx1);
  const int off1 = (gy1 << 7) + gx1;
  const int l2 = tid + 256;
  const int ly2 = l2 / 18, lx2 = l2 % 18;
  int gy2 = y0 - 1 + ly2; gy2 = gy2 < 0 ? 1 : (gy2 > 127 ? 126 : gy2);
  int gx2 = x0 - 1 + lx2; gx2 = gx2 < 0 ? 1 : (gx2 > 127 ? 126 : gx2);
  const int off2 = (gy2 << 7) + gx2;
  const bool has2 = (tid < 68);
  const int rb = ty * 18 + tx;
  const int gbase = vb + (z0 << 14) + ((y0 + ty) << 7) + (x0 + tx);

  float Y0[7], Y1[7], Y2[7];
  float rv1 = 0.f, rv2 = 0.f;
  float lmin = 3.4e38f, lmax = 0.f;

#define LOADR(ZS) {                                                         \
    const int zc_ = (ZS) > 127 ? 126 : (ZS);                                \
    const int za_ = vb + (zc_ << 14);                                       \
    rv1 = img[za_ + off1];                                                  \
    if (has2) rv2 = img[za_ + off2]; }

#define WRITELDS(BOFF) {                                                    \
    sb[(BOFF) + l1] = rv1;                                                  \
    if (has2) sb[(BOFF) + l2] = rv2; }

#define COMPY(P) {                                                          \
    const int o_ = (P) * 324 + rb;                                          \
    const float r00 = sb[o_],      r01 = sb[o_ + 1],  r02 = sb[o_ + 2];     \
    const float r10 = sb[o_ + 18], r11 = sb[o_ + 19], r12 = sb[o_ + 20];    \
    const float r20 = sb[o_ + 36], r21 = sb[o_ + 37], r22 = sb[o_ + 38];    \
    const float dx0 = r02 - r00, dx1 = r12 - r10, dx2 = r22 - r20;          \
    const float ux0 = r00 + r01 + r02, ux1 = r10 + r11 + r12,               \
                ux2 = r20 + r21 + r22;                                      \
    const float sx0 = ux0 + r01, sx1 = ux1 + r11, sx2 = ux2 + r21;          \
    Y##P[1] = dx0 + dx1 + dx2;           /* uydx */                         \
    Y##P[0] = Y##P[1] + dx1;             /* sydx */                         \
    Y##P[2] = sx2 - sx0;                 /* dysx */                         \
    Y##P[4] = sx0 + sx1 + sx2;           /* uysx */                         \
    Y##P[3] = Y##P[4] + sx1;             /* sysx */                         \
    Y##P[5] = ux2 - ux0;                 /* dyux */                         \
    Y##P[6] = (ux0 + ux2) + 2.f * ux1; } /* syux */

#define EMIT(I, P0, P1, P2) {                                               \
    const float E_ = Y##P0[0] + Y##P1[0] + Y##P2[0];                        \
    const float g1 = E_ + Y##P1[0];                                         \
    const float tA = Y##P0[1] + Y##P1[1] + Y##P2[1];                        \
    const float A_ = tA + Y##P1[1];                                         \
    const float D_ = Y##P0[2] + Y##P1[2] + Y##P2[2];                        \
    const float g2 = D_ + Y##P1[2];                                         \
    const float g3 = Y##P2[3] - Y##P0[3];                                   \
    const float C_ = Y##P2[4] - Y##P0[4];                                   \
    const float B_ = (Y##P0[5] + Y##P2[5]) + 2.f * Y##P1[5];                \
    const float F_ = Y##P2[6] - Y##P0[6];                                   \
    const float g4 = A_ - B_, g5 = A_ + B_;                                 \
    const float g6 = C_ - D_, g7 = C_ + D_;                                 \
    const float g8 = E_ - F_, g9 = E_ + F_;                                 \
    float ss_ = 9e-6f, t_;                                                  \
    t_ = g1 + 1e-6f; ss_ = fmaf(t_, t_, ss_);                               \
    t_ = g2 + 1e-6f; ss_ = fmaf(t_, t_, ss_);                               \
    t_ = g3 + 1e-6f; ss_ = fmaf(t_, t_, ss_);                               \
    t_ = g4 + 1e-6f; ss_ = fmaf(t_, t_, ss_);                               \
    t_ = g5 + 1e-6f; ss_ = fmaf(t_, t_, ss_);                               \
    t_ = g6 + 1e-6f; ss_ = fmaf(t_, t_, ss_);                               \
    t_ = g7 + 1e-6f; ss_ = fmaf(t_, t_, ss_);                               \
    t_ = g8 + 1e-6f; ss_ = fmaf(t_, t_, ss_);                               \
    t_ = g9 + 1e-6f; ss_ = fmaf(t_, t_, ss_);                               \
    const _Float16 gh = (_Float16)sqrtf(ss_);                               \
    gm[gbase + ((I) << 14)] = gh;                                           \
    const float gq = (float)gh;                                             \
    lmin = fminf(lmin, gq); lmax = fmaxf(lmax, gq); }

#define BODY(I, P0, P1, P2) {                                               \
    WRITELDS((P2) * 324);                                                   \
    LOADR(z0 + (I) + 2);                                                    \
    __syncthreads();                                                        \
    COMPY(P2);                                                              \
    EMIT(I, P0, P1, P2); }

  {
    const int zp = (z0 == 0) ? 1 : (z0 - 1);
    LOADR(zp);  WRITELDS(0);
    LOADR(z0);  WRITELDS(324);
    __syncthreads();
    COMPY(0);
    COMPY(1);
    LOADR(z0 + 1);                           // prime the pipeline
  }
  for (int ii = 0; ii < 30; ii += 3) {
    BODY(ii,     0, 1, 2);
    BODY(ii + 1, 1, 2, 0);
    BODY(ii + 2, 2, 0, 1);
  }
  BODY(30, 0, 1, 2);
  BODY(31, 1, 2, 0);

#undef BODY
#undef EMIT
#undef COMPY
#undef WRITELDS
#undef LOADR

  rmin[tid] = lmin; rmax[tid] = lmax;
  __syncthreads();
  for (int st = 128; st > 0; st >>= 1) {
    if (tid < st) {
      rmin[tid] = fminf(rmin[tid], rmin[tid + st]);
      rmax[tid] = fmaxf(rmax[tid], rmax[tid + st]);
    }
    __syncthreads();
  }
  if (tid == 0) {
    const int bin = (bx + (by << 3) + (bz << 6)) & 63;
    atomicMin(&ui[vol * 1024 + (bin << 4)], __float_as_uint(rmin[0]));
    atomicMax(&ui[2048 + vol * 1024 + (bin << 4)], __float_as_uint(rmax[0]));
  }
}

// ---- role: y-blur A -> B, 5-field 33KB h8 slab -----------------------------
__device__ __forceinline__ void blury_body(
    const _Float16* __restrict__ A, _Float16* __restrict__ B,
    const int z, const int yseg, const int batch) {
  __shared__ h8 s[5][26][16];   // 33,280 B
  const int tid = threadIdx.x;
  const int y0 = yseg << 4;
  const int b8 = batch << 18;                 // batch base in h8 units (HV/8)
  const h8* __restrict__ Ah = (const h8*)A;
  h8* __restrict__ Bh = (h8*)B;
  const int slice8 = b8 + (z << 11);          // h8 index of (b,z,0,0)
  for (int q = 0; q < 5; ++q) {
    const h8* __restrict__ Aq = Ah + (q << 19) + slice8;
    for (int l = tid; l < 416; l += 256) {    // 26 rows x 16 h8
      const int row = l >> 4, xc = l & 15;
      const int y = y0 - 5 + row;
      h8 v{};
      if ((unsigned)y < 128u) v = Aq[(y << 4) + xc];
      s[q][row][xc] = v;
    }
  }
  __syncthreads();
  const int xc = tid & 15;
  const int yo = tid >> 4;                    // 0..15
  const int wbase = slice8 + ((y0 + yo) << 4) + xc;
#pragma unroll
  for (int q = 0; q < 5; ++q) {
    h8 acc{};
#pragma unroll
    for (int k = 0; k < 11; ++k) {
      const _Float16 w = (_Float16)GW[k];
      acc += w * s[q][yo + k][xc];            // v_pk_fma_f16 x4
    }
    Bh[(q << 19) + wbase] = acc;
  }
}

// ---- role: mean |norm_p - norm_t| (h8 loads) -------------------------------
__device__ __forceinline__ void edge_body(
    const _Float16* __restrict__ gmP, const _Float16* __restrict__ gmT,
    const unsigned int* __restrict__ ui, double* __restrict__ absB,
    const int bidx) {
  __shared__ float rede[256];
  float mnp = 3.4e38f, mnt = 3.4e38f, mxp = 0.f, mxt = 0.f;
  for (int j = 0; j < 64; ++j) {
    mnp = fminf(mnp, __uint_as_float(ui[j << 4]));
    mnt = fminf(mnt, __uint_as_float(ui[1024 + (j << 4)]));
    mxp = fmaxf(mxp, __uint_as_float(ui[2048 + (j << 4)]));
    mxt = fmaxf(mxt, __uint_as_float(ui[3072 + (j << 4)]));
  }
  const float scp = 1.f / (mxp - mnp + 1e-6f);
  const float sct = 1.f / (mxt - mnt + 1e-6f);
  const h8* __restrict__ gp = (const h8*)gmP;
  const h8* __restrict__ gt = (const h8*)gmT;
  float lsum = 0.f;
  const int base = bidx << 9;                      // 512 h8 per block
#pragma unroll
  for (int i = 0; i < 2; ++i) {
    const int idx = base + (i << 8) + threadIdx.x;
    const h8 a = gp[idx];
    const h8 b = gt[idx];
#pragma unroll
    for (int j = 0; j < 8; ++j)
      lsum += fabsf(((float)a[j] - mnp) * scp - ((float)b[j] - mnt) * sct);
  }
  rede[threadIdx.x] = lsum;
  __syncthreads();
  for (int s = 128; s > 0; s >>= 1) {
    if (threadIdx.x < s) rede[threadIdx.x] += rede[threadIdx.x + s];
    __syncthreads();
  }
  if (threadIdx.x == 0)
    atomicAdd(&absB[(bidx & 63) << 3], (double)rede[0]);
}

// ---- L1: wblur || sobel (role-interleaved: bid%3 in {0,1}=wblur, 2=sobel) --
__global__ __launch_bounds__(256) void k_fused_a(
    const float* __restrict__ p, const float* __restrict__ t,
    _Float16* __restrict__ A, double* __restrict__ mseB,
    _Float16* __restrict__ gmP, _Float16* __restrict__ gmT,
    unsigned int* __restrict__ ui) {
  const int bid = blockIdx.x;                 // 0..3071
  const int r3 = bid % 3;
  if (r3 < 2) {
    wblur_body(p, t, A, mseB, (bid / 3) * 2 + r3);        // 0..2047
  } else {
    const int s = bid / 3;                                // 0..1023
    sobel_body(p, t, gmP, gmT, ui, s & 7, (s >> 3) & 7, s >> 6);
  }
}

// ---- L2: blur_y || edge_diff (same interleave) -----------------------------
__global__ __launch_bounds__(256) void k_fused_b(
    const _Float16* __restrict__ A, _Float16* __restrict__ B,
    const _Float16* __restrict__ gmP, const _Float16* __restrict__ gmT,
    const unsigned int* __restrict__ ui, double* __restrict__ absB) {
  const int bid = blockIdx.x;                 // 0..3071
  const int r3 = bid % 3;
  if (r3 < 2) {
    const int idx = (bid / 3) * 2 + r3;                   // 0..2047
    blury_body(A, B, idx & 127, (idx >> 7) & 7, idx >> 10);
  } else {
    edge_body(gmP, gmT, ui, absB, bid / 3);               // 0..1023
  }
}

// ---- K2b: z-blur B, h8 slab, packed-fp16 taps + fp32 SSIM map + reduce -----
__global__ __launch_bounds__(256) void k_zblur_ssim(
    const _Float16* __restrict__ B, double* __restrict__ ssimB) {
  __shared__ h8 s[5][26][16];   // 33,280 B
  __shared__ float red[256];
  const int tid = threadIdx.x;
  const int y  = blockIdx.x;
  const int z0 = blockIdx.y << 4;
  const int b8 = blockIdx.z << 18;            // h8 units
  const h8* __restrict__ Bh = (const h8*)B;
  const int col8 = b8 + (y << 4);
  for (int q = 0; q < 5; ++q) {
    const h8* __restrict__ Bq = Bh + (q << 19) + col8;
    for (int l = tid; l < 416; l += 256) {    // 26 z-rows x 16 h8
      const int row = l >> 4, xc = l & 15;
      const int zz = z0 - 5 + row;
      h8 v{};
      if ((unsigned)zz < 128u) v = Bq[(zz << 11) + xc];
      s[q][row][xc] = v;
    }
  }
  __syncthreads();
  const int xc = tid & 15;
  const int zo = tid >> 4;                    // 0..15
  h8 m[5];
#pragma unroll
  for (int q = 0; q < 5; ++q) {
    h8 acc{};
#pragma unroll
    for (int k = 0; k < 11; ++k) {
      const _Float16 w = (_Float16)GW[k];
      acc += w * s[q][zo + k][xc];
    }
    m[q] = acc;
  }
  float lsum = 0.f;
#pragma unroll
  for (int j = 0; j < 8; ++j) {
    const float mp  = (float)m[0][j];
    const float mt  = (float)m[1][j];
    const float epp = (float)m[2][j];
    const float ett = (float)m[3][j];
    const float ept = (float)m[4][j];
    const float mp2 = mp * mp, mt2 = mt * mt, mpt = mp * mt;
    const float num = (2.f * mpt + 1e-4f) * (2.f * (ept - mpt) + 9e-4f);
    const float den = (mp2 + mt2 + 1e-4f) * ((epp - mp2) + (ett - mt2) + 9e-4f);
    lsum += num / den;
  }
  red[tid] = lsum;
  __syncthreads();
  for (int st = 128; st > 0; st >>= 1) {
    if (tid < st) red[tid] += red[tid + st];
    __syncthreads();
  }
  if (tid == 0) {
    const int bin = (blockIdx.x + (blockIdx.y << 3) + blockIdx.z) & 63;
    atomicAdd(&ssimB[bin << 3], (double)red[0]);
  }
}

// ---- final: fold bins, emit the 4 scalars ----------------------------------
__global__ void k_final(const double* __restrict__ dbl, float* __restrict__ out) {
  if (threadIdx.x == 0 && blockIdx.x == 0) {
    double ms = 0.0, ss = 0.0, ab = 0.0;
    for (int j = 0; j < 64; ++j) {
      ms += dbl[j << 3];
      ss += dbl[512 + (j << 3)];
      ab += dbl[1024 + (j << 3)];
    }
    const double N = 4194304.0;
    const double mse   = ms / N;
    const double ssiml = 1.0 - ss / N;
    const double gme   = 1e-6 + ab / N;
    const double total = mse + ssiml + 0.7 * gme;
    out[0] = (float)total;
    out[1] = (float)mse;
    out[2] = (float)ssiml;
    out[3] = (float)gme;
  }
}

extern "C" void kernel_launch(void* const* d_in, const int* in_sizes, int n_in,
                              void* d_out, int out_size, void* d_ws, size_t ws_size,
                              hipStream_t stream) {
  const float* p = (const float*)d_in[0];
  const float* t = (const float*)d_in[1];
  _Float16* A = (_Float16*)d_ws;                    // 5*VOL halfs = 40 MiB
  _Float16* B = A + (size_t)5 * VOL;                // 40 MiB
  char* accb = (char*)d_ws + (size_t)20 * VOL;      // @80 MiB
  double* dbl = (double*)accb;
  unsigned int* ui = (unsigned int*)(accb + 12288);
  _Float16* gmP = (_Float16*)((char*)d_ws + 88080384);  // @84 MiB, 16 MiB
  _Float16* gmT = gmP + VOL;
  float* out = (float*)d_out;

  k_init<<<16, 256, 0, stream>>>(dbl, ui);
  k_fused_a<<<3072, 256, 0, stream>>>(p, t, A, dbl, gmP, gmT, ui);
  k_fused_b<<<3072, 256, 0, stream>>>(A, B, gmP, gmT, ui, dbl + 1024);
  k_zblur_ssim<<<dim3(128, 8, 2), 256, 0, stream>>>(B, dbl + 512);
  k_final<<<1, 64, 0, stream>>>(dbl, out);
}